// Round 3
// baseline (445.624 us; speedup 1.0000x reference)
//
#include <hip/hip_runtime.h>
#include <math.h>

// Problem constants (match reference)
constexpr int C   = 6;
constexpr int NR  = 2048;
constexpr int NC  = 2048;
constexpr int KS  = 10;
constexpr int PAD = 4;            // top/left circular halo

// Streaming config: thread owns 8 output cols, block (256 thr) owns full 2048-col
// rows; block streams a 16-row output strip (25 input rows incl. 9 halo rows).
constexpr int CPT   = 8;          // cols per thread
constexpr int R     = 16;         // output rows per block
constexpr int NITER = R + KS - 1; // 25 streamed H-rows

__device__ __constant__ float MTFf[C] = {0.38f, 0.34f, 0.34f, 0.26f, 0.22f, 0.23f};

__global__ __launch_bounds__(256, 3)   // cap VGPR ~170: 3 blocks/CU, 12 waves/CU
void s2_blur_stream(const float* __restrict__ x, float* __restrict__ out)
{
    const int t  = threadIdx.x;
    const int c  = blockIdx.y;
    const int r0 = blockIdx.x * R;

    const float* xc = x   + (size_t)c * NR * NC;
    float*       oc = out + (size_t)c * NR * NC;

    // per-thread fp32 weights (err ~1e-6 << 3.25e-2 threshold)
    float w[KS];
    {
        float mtf    = MTFf[c];
        float sig    = 2.0f * sqrtf(-2.0f * logf(mtf) / (float)(M_PI * M_PI));
        float inv2s2 = 1.0f / (2.0f * sig * sig);
        float s = 0.0f;
        #pragma unroll
        for (int d = 0; d < KS; ++d) {
            float cd = -4.5f + (float)d;
            w[d] = expf(-cd * cd * inv2s2);
            s += w[d];
        }
        #pragma unroll
        for (int d = 0; d < KS; ++d) w[d] /= s;
    }

    const int  cb   = t * CPT - PAD;               // input window start col
    const bool edge = (t == 0) || (t == 255);      // window wraps around cols

    // 10-deep accumulator ring: slot (k+o)%10 holds block-relative out row k+o-9
    float acc[10][CPT];
    #pragma unroll
    for (int s = 0; s < 10; ++s)
        #pragma unroll
        for (int q = 0; q < CPT; ++q) acc[s][q] = 0.0f;

    // row loader: v[0..16] = x[row gr][cb .. cb+16] (wrapped for edge threads)
    auto load_row = [&](int k, float v[17]) {
        const int gr = (r0 - PAD + k) & (NR - 1);
        const float* row = xc + (size_t)gr * NC;
        if (!edge) {
            // (8t-4)*4 bytes is 16B-aligned -> 4x global_load_dwordx4 + 1 dword
            const float4* p = (const float4*)(row + cb);
            float4 a = p[0], b = p[1], d2 = p[2], d3 = p[3];
            v[0]=a.x;   v[1]=a.y;   v[2]=a.z;   v[3]=a.w;
            v[4]=b.x;   v[5]=b.y;   v[6]=b.z;   v[7]=b.w;
            v[8]=d2.x;  v[9]=d2.y;  v[10]=d2.z; v[11]=d2.w;
            v[12]=d3.x; v[13]=d3.y; v[14]=d3.z; v[15]=d3.w;
            v[16] = row[cb + 16];
        } else {
            #pragma unroll
            for (int q = 0; q < 17; ++q)
                v[q] = row[(cb + q) & (NC - 1)];
        }
    };

    float vc[17];
    load_row(0, vc);

    #pragma unroll
    for (int k = 0; k < NITER; ++k) {
        // prefetch next input row before consuming this one (loads stay in flight
        // across ~130 FMAs; no barrier anywhere in the kernel)
        float vn[17];
        if (k + 1 < NITER) load_row(k + 1, vn);

        // horizontal pass for input row k: H[o] = sum_d w[d] * v[o+d]
        float H[CPT];
        #pragma unroll
        for (int o = 0; o < CPT; ++o) {
            float a = 0.0f;
            #pragma unroll
            for (int d = 0; d < KS; ++d) a = fmaf(w[d], vc[o + d], a);
            H[o] = a;
        }

        // vertical scatter: H row k contributes w[9-o] to out row j = k+o-9
        #pragma unroll
        for (int o = 0; o < 10; ++o) {
            const int j = k + o - 9;
            if (j >= 0 && j < R) {
                const int   s  = (k + o) % 10;
                const float wd = w[9 - o];
                #pragma unroll
                for (int q = 0; q < CPT; ++q)
                    acc[s][q] = fmaf(wd, H[q], acc[s][q]);
            }
        }

        // emit finished row j = k-9 (slot k%10), then recycle the slot
        if (k >= KS - 1) {
            const int s = k % 10;
            float* orow = oc + (size_t)(r0 + k - 9) * NC + t * CPT;
            ((float4*)orow)[0] = make_float4(acc[s][0], acc[s][1], acc[s][2], acc[s][3]);
            ((float4*)orow)[1] = make_float4(acc[s][4], acc[s][5], acc[s][6], acc[s][7]);
            #pragma unroll
            for (int q = 0; q < CPT; ++q) acc[s][q] = 0.0f;
        }

        #pragma unroll
        for (int q = 0; q < 17; ++q) vc[q] = vn[q];
    }
}

extern "C" void kernel_launch(void* const* d_in, const int* in_sizes, int n_in,
                              void* d_out, int out_size, void* d_ws, size_t ws_size,
                              hipStream_t stream) {
    const float* x = (const float*)d_in[0];
    float* out = (float*)d_out;
    dim3 grid(NR / R, C);             // 128 x 6 = 768 blocks = 3 blocks/CU exactly
    dim3 block(256);
    s2_blur_stream<<<grid, block, 0, stream>>>(x, out);
}

// Round 4
// 218.915 us; speedup vs baseline: 2.0356x; 2.0356x over previous
//
#include <hip/hip_runtime.h>
#include <math.h>

// Problem constants (match reference)
constexpr int C   = 6;
constexpr int NR  = 2048;
constexpr int NC  = 2048;
constexpr int KS  = 10;
constexpr int PAD = 4;               // top/left circular halo

// Tiling: 64 wide x 32 tall per block -> LDS 23.1 KB -> 6 blocks/CU (24 waves/CU).
// (R1 used 64x64 -> 41.5 KB -> only 3 blocks/CU; phase serialization left HBM
// idle 2/3 of the time. More resident blocks desynchronize the phases.)
constexpr int TX = 64;
constexpr int TY = 32;
constexpr int RAW_W = TX + KS - 1;   // 73
constexpr int RAW_H = TY + KS - 1;   // 41
constexpr int RAW_STRIDE = 77;       // odd stride -> worst-case 2-way LDS aliasing (free)

__device__ __constant__ float MTFf[C] = {0.38f, 0.34f, 0.34f, 0.26f, 0.22f, 0.23f};

__global__ __launch_bounds__(256, 6)   // 6 waves/EU = 24 waves/CU; VGPR cap 80 (R1 needed 68)
void s2_gaussian_blur_kernel(const float* __restrict__ x, float* __restrict__ out)
{
    __shared__ float raw[RAW_H * RAW_STRIDE];   // 41*77*4 = 12.6 KB
    __shared__ float Ht[RAW_H * TX];            // 41*64*4 = 10.5 KB

    const int tid = threadIdx.x;
    const int c   = blockIdx.z;
    const int i0  = blockIdx.y * TY;
    const int j0  = blockIdx.x * TX;

    const float* xc = x   + (size_t)c * NR * NC;
    float*       oc = out + (size_t)c * NR * NC;

    // ---- per-thread fp32 weights (verified: absmax 0.0039 << 0.0325 threshold) ----
    float w[KS];
    {
        float mtf    = MTFf[c];
        float sig    = 2.0f * sqrtf(-2.0f * logf(mtf) / (float)(M_PI * M_PI));
        float inv2s2 = 1.0f / (2.0f * sig * sig);
        float s = 0.0f;
        #pragma unroll
        for (int d = 0; d < KS; ++d) {
            float cd = -4.5f + (float)d;
            w[d] = expf(-cd * cd * inv2s2);
            s += w[d];
        }
        #pragma unroll
        for (int d = 0; d < KS; ++d) w[d] /= s;
    }

    // ---- Phase 1: load raw tile (wrap addressing); ~12 independent loads/thread ----
    for (int idx = tid; idx < RAW_H * RAW_W; idx += 256) {
        int r  = idx / RAW_W;
        int cc = idx - r * RAW_W;
        int gr = (i0 + r  - PAD + NR) & (NR - 1);
        int gc = (j0 + cc - PAD + NC) & (NC - 1);
        raw[r * RAW_STRIDE + cc] = xc[(size_t)gr * NC + gc];
    }
    __syncthreads();

    // ---- Phase 2: horizontal pass, 41 rows x 8 col-groups = 328 items ----
    for (int item = tid; item < RAW_H * (TX / 8); item += 256) {
        int r = item >> 3;
        int g = item & 7;
        int base = r * RAW_STRIDE + g * 8;
        float v[17];
        #pragma unroll
        for (int k = 0; k < 17; ++k) v[k] = raw[base + k];
        float acc[8];
        #pragma unroll
        for (int o = 0; o < 8; ++o) {
            float a = 0.f;
            #pragma unroll
            for (int d = 0; d < KS; ++d) a = fmaf(w[d], v[o + d], a);
            acc[o] = a;
        }
        float4* q = (float4*)&Ht[r * TX + g * 8];   // Ht rows are 16B-aligned
        q[0] = make_float4(acc[0], acc[1], acc[2], acc[3]);
        q[1] = make_float4(acc[4], acc[5], acc[6], acc[7]);
    }
    __syncthreads();

    // ---- Phase 3: vertical pass; thread owns col jj, 8 rows; exactly one pass ----
    {
        const int jj = tid & 63;
        const int rg = tid >> 6;          // 0..3 -> rows [8rg, 8rg+8)
        int base = rg * 8 * TX + jj;
        float v[17];
        #pragma unroll
        for (int k = 0; k < 17; ++k) v[k] = Ht[base + k * TX];  // 2-way aliasing: free
        #pragma unroll
        for (int o = 0; o < 8; ++o) {
            float a = 0.f;
            #pragma unroll
            for (int d = 0; d < KS; ++d) a = fmaf(w[d], v[o + d], a);
            oc[(size_t)(i0 + rg * 8 + o) * NC + (j0 + jj)] = a;
        }
    }
}

extern "C" void kernel_launch(void* const* d_in, const int* in_sizes, int n_in,
                              void* d_out, int out_size, void* d_ws, size_t ws_size,
                              hipStream_t stream) {
    const float* x = (const float*)d_in[0];
    float* out = (float*)d_out;
    dim3 grid(NC / TX, NR / TY, C);   // 32 x 64 x 6 = 12288 blocks
    dim3 block(256);
    s2_gaussian_blur_kernel<<<grid, block, 0, stream>>>(x, out);
}

// Round 5
// 183.188 us; speedup vs baseline: 2.4326x; 1.1950x over previous
//
#include <hip/hip_runtime.h>
#include <math.h>

// Problem constants (match reference)
constexpr int C   = 6;
constexpr int NR  = 2048;
constexpr int NC  = 2048;
constexpr int KS  = 10;
constexpr int PAD = 4;              // top/left circular halo

// Streaming config: thread owns 4 output cols (one float4); 2 blocks in x cover a
// full 2048-col row; block streams a 32-row output strip (41 input rows w/ halo).
// No LDS, no barriers: H-pass from global (coalesced dwordx4, overlapping windows
// served by L1), V-pass in a 10-deep register ring. All row base addressing is
// wave-uniform -> SALU; per-lane col offsets are loop-invariant.
constexpr int R    = 32;            // output rows per block
constexpr int NIT  = R + KS - 1;    // 41 streamed H-rows
constexpr int CPT  = 4;             // cols per thread
constexpr int BW   = 256 * CPT;     // 1024 cols per block

__device__ __constant__ float MTFf[C] = {0.38f, 0.34f, 0.34f, 0.26f, 0.22f, 0.23f};

__global__ __launch_bounds__(256, 3)   // VGPR cap ~168; ~95 live -> no spills (R3 lesson)
void s2_blur_ring(const float* __restrict__ x, float* __restrict__ out)
{
    const int t  = threadIdx.x;
    const int c  = blockIdx.z;
    const int r0 = blockIdx.y * R;
    const int jt = blockIdx.x * BW + t * CPT;   // first output col of this thread

    const float* xc = x   + (size_t)c * NR * NC;
    float*       oc = out + (size_t)c * NR * NC;

    // ---- per-thread fp32 weights (verified absmax 0.0039 << 0.0325) ----
    float w[KS];
    {
        float mtf    = MTFf[c];
        float sig    = 2.0f * sqrtf(-2.0f * logf(mtf) / (float)(M_PI * M_PI));
        float inv2s2 = 1.0f / (2.0f * sig * sig);
        float s = 0.0f;
        #pragma unroll
        for (int d = 0; d < KS; ++d) {
            float cd = -4.5f + (float)d;
            w[d] = expf(-cd * cd * inv2s2);
            s += w[d];
        }
        #pragma unroll
        for (int d = 0; d < KS; ++d) w[d] /= s;
    }

    // ---- per-lane wrapped float4-group offsets (loop-invariant; wrap is a
    // multiple of 4 floats so a 16B group never splits) ----
    const int off0 = (jt - PAD +  0 + NC) & (NC - 1);
    const int off1 = (jt - PAD +  4 + NC) & (NC - 1);
    const int off2 = (jt - PAD +  8 + NC) & (NC - 1);
    const int off3 = (jt - PAD + 12 + NC) & (NC - 1);

    // V-pass accumulator ring: slot m%10 holds strip-row m in flight
    float acc[KS][CPT];
    #pragma unroll
    for (int s = 0; s < KS; ++s)
        #pragma unroll
        for (int q = 0; q < CPT; ++q) acc[s][q] = 0.0f;

    // prime the pipeline: row k=0
    float4 f0, f1, f2, f3;
    {
        const float* rp = xc + (size_t)((r0 - PAD + NR) & (NR - 1)) * NC;
        f0 = *(const float4*)(rp + off0);
        f1 = *(const float4*)(rp + off1);
        f2 = *(const float4*)(rp + off2);
        f3 = *(const float4*)(rp + off3);
    }

    #pragma unroll
    for (int k = 0; k < NIT; ++k) {
        // prefetch row k+1 (loads in flight across ~85 FMAs + wave TLP)
        float4 g0, g1, g2, g3;
        if (k + 1 < NIT) {
            const float* rp = xc + (size_t)((r0 - PAD + k + 1) & (NR - 1)) * NC;
            g0 = *(const float4*)(rp + off0);
            g1 = *(const float4*)(rp + off1);
            g2 = *(const float4*)(rp + off2);
            g3 = *(const float4*)(rp + off3);
        }

        // ---- H-pass for row k: H[q] = sum_d w[d] * window[q+d] ----
        const float f[16] = {f0.x, f0.y, f0.z, f0.w,
                             f1.x, f1.y, f1.z, f1.w,
                             f2.x, f2.y, f2.z, f2.w,
                             f3.x, f3.y, f3.z, f3.w};
        float H[CPT];
        #pragma unroll
        for (int q = 0; q < CPT; ++q) {
            float a = 0.0f;
            #pragma unroll
            for (int d = 0; d < KS; ++d) a = fmaf(w[d], f[q + d], a);
            H[q] = a;
        }

        // ---- V-pass ring update: H row k feeds strip rows m = k-o, weight w[o] ----
        #pragma unroll
        for (int o = 0; o < KS; ++o) {
            const int m = k - o;
            if (m >= 0 && m < R) {
                const int s = m % KS;
                #pragma unroll
                for (int q = 0; q < CPT; ++q)
                    acc[s][q] = fmaf(w[o], H[q], acc[s][q]);
            }
        }

        // ---- emit finished strip row m = k-9 ----
        if (k >= KS - 1) {
            const int m = k - (KS - 1);
            const int s = m % KS;
            float* orow = oc + (size_t)(r0 + m) * NC;   // wave-uniform base
            *(float4*)(orow + jt) = make_float4(acc[s][0], acc[s][1], acc[s][2], acc[s][3]);
            #pragma unroll
            for (int q = 0; q < CPT; ++q) acc[s][q] = 0.0f;
        }

        f0 = g0; f1 = g1; f2 = g2; f3 = g3;
    }
}

extern "C" void kernel_launch(void* const* d_in, const int* in_sizes, int n_in,
                              void* d_out, int out_size, void* d_ws, size_t ws_size,
                              hipStream_t stream) {
    const float* x = (const float*)d_in[0];
    float* out = (float*)d_out;
    dim3 grid(NC / BW, NR / R, C);   // 2 x 64 x 6 = 768 blocks = 3 blocks/CU exactly
    dim3 block(256);
    s2_blur_ring<<<grid, block, 0, stream>>>(x, out);
}